// Round 14
// baseline (92.497 us; speedup 1.0000x reference)
//
#include <hip/hip_runtime.h>

#define NQ 32768
#define NP 8192
#define FD 32
#define KNN 8
#define WPB 8
#define TB 512
#define QBLK 32            // queries per block: 2 groups of 16
#define NTILE (NP / 16)    // 512 point-tiles
#define QTILE (NTILE / 4)  // 128 tiles per quarter-wave
#define ATILE 32           // phase-A tiles per quarter (512 points)
#define CAP 128            // candidate capacity (stats identical to r12/r13: E~33)
#define MARGIN 1e-2f       // >> 2*e1+2*e2 ~ 4e-3 worst-corner bf16-split error

typedef unsigned long long u64;
typedef short short8 __attribute__((ext_vector_type(8)));
typedef float f32x4 __attribute__((ext_vector_type(4)));

__device__ __forceinline__ unsigned short f2bf(float f) {   // RNE f32->bf16
    unsigned u = __float_as_uint(f);
    return (unsigned short)((u + 0x7FFFu + ((u >> 16) & 1u)) >> 16);
}
__device__ __forceinline__ float bf2f(unsigned short s) {
    return __uint_as_float(((unsigned)s) << 16);
}

__device__ __forceinline__ u64 shfl_xor_u64(u64 k, int j) {
    unsigned lo = __shfl_xor((unsigned)k, j);
    unsigned hi = __shfl_xor((unsigned)(k >> 32), j);
    return ((u64)hi << 32) | lo;
}
__device__ __forceinline__ u64 sort64_u64(u64 key, int lane) {   // r5-verified
    for (int k2 = 2; k2 <= 64; k2 <<= 1)
        for (int j = k2 >> 1; j > 0; j >>= 1) {
            u64 o = shfl_xor_u64(key, j);
            bool keepMin = ((lane & k2) == 0) == ((lane & j) == 0);
            key = ((o < key) == keepMin) ? o : key;
        }
    return key;
}
__device__ __forceinline__ float eighth_smallest64(float v, int lane) {  // r6-verified
    for (int k2 = 2; k2 <= 64; k2 <<= 1)
        for (int j = k2 >> 1; j > 0; j >>= 1) {
            float o = __shfl_xor(v, j);
            bool keepMin = ((lane & k2) == 0) == ((lane & j) == 0);
            v = ((o < v) == keepMin) ? o : v;
        }
    return __uint_as_float((unsigned)__builtin_amdgcn_readlane((int)__float_as_uint(v), 7));
}

// prepack: per point 16 bf16 K-slots [mh_x,mh_y,mh_z, mh_x,mh_y,mh_z, ml_x,ml_y,ml_z,
// pnh, pnl, 0..0] where m = -2p (split), pn screen-space fmaf norm (split).
__global__ void k_prepack(const float* __restrict__ points, unsigned short* __restrict__ ptsB) {
    int i = blockIdx.x * 256 + threadIdx.x;
    float px = points[i * 3 + 0], py = points[i * 3 + 1], pz = points[i * 3 + 2];
    float mx = -2.0f * px, my = -2.0f * py, mz = -2.0f * pz;
    float pn = __builtin_fmaf(pz, pz, __builtin_fmaf(py, py, px * px));
    unsigned short mhx = f2bf(mx), mhy = f2bf(my), mhz = f2bf(mz);
    unsigned short mlx = f2bf(mx - bf2f(mhx)), mly = f2bf(my - bf2f(mhy)), mlz = f2bf(mz - bf2f(mhz));
    unsigned short pnh = f2bf(pn), pnl = f2bf(pn - bf2f(pnh));
    unsigned s0 = (unsigned)mhx | ((unsigned)mhy << 16);   // k0,k1
    unsigned s1 = (unsigned)mhz | ((unsigned)mhx << 16);   // k2,k3
    unsigned s2 = (unsigned)mhy | ((unsigned)mhz << 16);   // k4,k5
    unsigned s3 = (unsigned)mlx | ((unsigned)mly << 16);   // k6,k7
    unsigned s4 = (unsigned)mlz | ((unsigned)pnh << 16);   // k8,k9
    unsigned s5 = (unsigned)pnl;                           // k10,k11
    uint4* o = (uint4*)(ptsB + i * 16);
    o[0] = make_uint4(s0, s1, s2, s3);
    o[1] = make_uint4(s4, s5, 0u, 0u);
}

__global__ __launch_bounds__(TB) void knn_kernel(
    const float* __restrict__ xyz, const float* __restrict__ points,
    const float* __restrict__ feats, const unsigned short* __restrict__ ptsB,
    float* __restrict__ out)
{
#pragma clang fp contract(off)   // np-exact paths: explicit mul/add; fast paths: explicit fmaf
    __shared__ float smin[2][16][64];             // 8 KB col-mins
    __shared__ float stau[QBLK];
    __shared__ unsigned short sidx16[QBLK * CAP]; // 8 KB candidate indices
    __shared__ int scnt[QBLK];

    const int t = threadIdx.x, lane = t & 63, wid = t >> 6;
    const int grp = wid >> 2, quarter = wid & 3;
    const int col = lane & 15, kb = lane >> 4;
    const int qbase_g = blockIdx.x * QBLK + grp * 16;

    if (t < QBLK) scnt[t] = 0;

    // ---- A fragment: 16 queries, K-slots [qh_x,qh_y,qh_z, ql_x,ql_y,ql_z,
    //      qh_x,qh_y | qh_z, 1, 1, 0...] ; lane row=col=lane&15, k=(lane>>4)*8+i ----
    short8 af = 0;
    {
        int qid = qbase_g + col;
        float a = xyz[qid * 3 + 0], b = xyz[qid * 3 + 1], c = xyz[qid * 3 + 2];
        unsigned short qhx = f2bf(a), qhy = f2bf(b), qhz = f2bf(c);
        unsigned short qlx = f2bf(a - bf2f(qhx)), qly = f2bf(b - bf2f(qhy)), qlz = f2bf(c - bf2f(qhz));
        if (kb == 0) {
            af[0] = (short)qhx; af[1] = (short)qhy; af[2] = (short)qhz;
            af[3] = (short)qlx; af[4] = (short)qly; af[5] = (short)qlz;
            af[6] = (short)qhx; af[7] = (short)qhy;
        } else if (kb == 1) {
            af[0] = (short)qhz; af[1] = (short)0x3F80; af[2] = (short)0x3F80;  // bf16(1.0)
        }
    }

    const int tb0 = quarter * QTILE;

    // ---- Phase A: MFMA min-scan over first ATILE tiles of this quarter ----
    f32x4 mnA;
    mnA[0] = mnA[1] = mnA[2] = mnA[3] = __builtin_inff();
#pragma unroll 4
    for (int s = 0; s < ATILE; ++s) {
        int tb = tb0 + s;
        short8 bf8 = 0;
        if (kb < 2) bf8 = *(const short8*)(ptsB + tb * 256 + col * 16 + kb * 8);
        f32x4 acc = {0.f, 0.f, 0.f, 0.f};
        acc = __builtin_amdgcn_mfma_f32_16x16x32_bf16(af, bf8, acc, 0, 0, 0);
#pragma unroll
        for (int j = 0; j < 4; ++j) mnA[j] = fminf(mnA[j], acc[j]);
    }
    // col-mins: smin[grp][row][quarter*16+col]; row=(lane>>4)*4+j  (m89 C/D layout)
#pragma unroll
    for (int j = 0; j < 4; ++j) smin[grp][kb * 4 + j][quarter * 16 + col] = mnA[j];
    __syncthreads();

    // ---- tau: per query, 8th smallest of 64 col-mins (32-pt disjoint subsets; r12/r13 stats)
#pragma unroll
    for (int j2 = 0; j2 < 4; ++j2) {
        int qloc = wid * 4 + j2;
        float v = smin[qloc >> 4][qloc & 15][lane];
        float t8 = eighth_smallest64(v, lane);
        if (lane == 0) stau[qloc] = t8 + MARGIN;
    }
    __syncthreads();
    float tau4[4];
#pragma unroll
    for (int j = 0; j < 4; ++j) tau4[j] = stau[grp * 16 + kb * 4 + j];

    // ---- Phase B: MFMA screen over this quarter's 128 tiles (incl. A tiles) ----
#pragma unroll 4
    for (int s = 0; s < QTILE; ++s) {
        int tb = tb0 + s;
        short8 bf8 = 0;
        if (kb < 2) bf8 = *(const short8*)(ptsB + tb * 256 + col * 16 + kb * 8);
        f32x4 acc = {0.f, 0.f, 0.f, 0.f};
        acc = __builtin_amdgcn_mfma_f32_16x16x32_bf16(af, bf8, acc, 0, 0, 0);
        float d0 = acc[0] - tau4[0], d1 = acc[1] - tau4[1];
        float d2 = acc[2] - tau4[2], d3 = acc[3] - tau4[3];
        float dm = fminf(fminf(d0, d1), fminf(d2, d3));
        if (__builtin_expect(dm <= 0.0f, 0)) {
#pragma unroll
            for (int j = 0; j < 4; ++j) {
                if (acc[j] <= tau4[j]) {
                    int qloc = grp * 16 + kb * 4 + j;
                    int slot = atomicAdd(&scnt[qloc], 1);
                    if (slot < CAP) sidx16[qloc * CAP + slot] = (unsigned short)(tb * 16 + col);
                }
            }
        }
    }
    __syncthreads();

    // ---- Phase C: np-exact d2 recompute, u64 sort(s), top-8, output (r10-13 verified) ----
    const float4* feats4 = (const float4*)feats;
    float4* outf4 = (float4*)(out + (long)NQ * KNN * 3);
#pragma unroll 1
    for (int qq = 0; qq < 4; ++qq) {
        int wq = wid * 4 + qq;                       // block-local query
        int q  = blockIdx.x * QBLK + wq;             // global query id
        float a = xyz[q * 3 + 0], b = xyz[q * 3 + 1], c = xyz[q * 3 + 2];
        float qn = (a * a + b * b) + c * c;          // np-exact
        int cnt = scnt[wq]; if (cnt > CAP) cnt = CAP;

        u64 key1 = ~0ull;
        if (lane < cnt) {
            int idx = sidx16[wq * CAP + lane];
            float px = points[idx * 3 + 0], py = points[idx * 3 + 1], pz = points[idx * 3 + 2];
            float pn  = (px * px + py * py) + pz * pz;                 // np-exact
            float dot = __builtin_fmaf(c, pz, __builtin_fmaf(b, py, a * px));
            float d2v = (qn - 2.0f * dot) + pn;
            unsigned bb = __float_as_uint(d2v);
            unsigned mk = (bb & 0x80000000u) ? ~bb : (bb | 0x80000000u);
            key1 = ((u64)mk << 32) | (unsigned)idx;
        }
        u64 v = sort64_u64(key1, lane);

        if (cnt > 64) {                              // wave-uniform, rare
            u64 key2 = ~0ull;
            if (lane + 64 < cnt) {
                int idx = sidx16[wq * CAP + 64 + lane];
                float px = points[idx * 3 + 0], py = points[idx * 3 + 1], pz = points[idx * 3 + 2];
                float pn  = (px * px + py * py) + pz * pz;
                float dot = __builtin_fmaf(c, pz, __builtin_fmaf(b, py, a * px));
                float d2v = (qn - 2.0f * dot) + pn;
                unsigned bb = __float_as_uint(d2v);
                unsigned mk = (bb & 0x80000000u) ? ~bb : (bb | 0x80000000u);
                key2 = ((u64)mk << 32) | (unsigned)idx;
            }
            u64 s2 = sort64_u64(key2, lane);
            int src = (15 - lane) & 63;
            unsigned lo2 = __shfl((unsigned)s2, src);
            unsigned hi2 = __shfl((unsigned)(s2 >> 32), src);
            u64 kr = ((u64)hi2 << 32) | lo2;
            u64 m = (lane < 8) ? v : ((lane < 16) ? kr : ~0ull);
#pragma unroll
            for (int j = 8; j > 0; j >>= 1) {
                u64 o = shfl_xor_u64(m, j);
                bool low = (lane & j) == 0;
                m = low ? (o < m ? o : m) : (o < m ? m : o);
            }
            v = m;
        }

        // lanes 0..7 hold top-8 ascending (r5/r6-verified output layout)
        int nb = __shfl((int)(unsigned)v, lane >> 3);
        outf4[(long)q * (KNN * FD / 4) + lane] = feats4[(long)nb * (FD / 4) + (lane & 7)];
        int j2 = lane / 3;
        int nb2 = __shfl((int)(unsigned)v, j2);
        if (lane < 24) {
            out[(long)q * (KNN * 3) + lane] = points[nb2 * 3 + (lane - j2 * 3)];
        }
    }
}

extern "C" void kernel_launch(void* const* d_in, const int* in_sizes, int n_in,
                              void* d_out, int out_size, void* d_ws, size_t ws_size,
                              hipStream_t stream) {
    const float* xyz    = (const float*)d_in[0];
    const float* points = (const float*)d_in[1];
    const float* feats  = (const float*)d_in[2];
    float* out = (float*)d_out;
    unsigned short* ptsB = (unsigned short*)d_ws;   // 256 KB scratch

    hipLaunchKernelGGL(k_prepack, dim3(NP / 256), dim3(256), 0, stream, points, ptsB);
    hipLaunchKernelGGL(knn_kernel, dim3(NQ / QBLK), dim3(TB), 0, stream,
                       xyz, points, feats, ptsB, out);
}

// Round 15
// 78.488 us; speedup vs baseline: 1.1785x; 1.1785x over previous
//
#include <hip/hip_runtime.h>

#define NQ 32768
#define NP 8192
#define FD 32
#define KNN 8
#define QW 4                 // queries per wave
#define WPB 8                // waves per block
#define TB 512
#define QBLK (QW * WPB)      // 32 queries per block
#define CHP 512              // points per staged chunk (double-buffered)
#define ACH 4                // phase-A chunks (2048 points, min-only)
#define NCH (NP / CHP)       // 16 screen chunks
#define NC (ACH + NCH)       // 20 pipeline steps
#define CAP 128              // candidate capacity (E~32, r12/r13-validated)

typedef unsigned long long u64;

__device__ __forceinline__ u64 shfl_xor_u64(u64 k, int j) {
    unsigned lo = __shfl_xor((unsigned)k, j);
    unsigned hi = __shfl_xor((unsigned)(k >> 32), j);
    return ((u64)hi << 32) | lo;
}
// full 64-lane bitonic sort, ascending by lane (r5-verified pattern)
__device__ __forceinline__ u64 sort64_u64(u64 key, int lane) {
    for (int k2 = 2; k2 <= 64; k2 <<= 1)
        for (int j = k2 >> 1; j > 0; j >>= 1) {
            u64 o = shfl_xor_u64(key, j);
            bool keepMin = ((lane & k2) == 0) == ((lane & j) == 0);
            key = ((o < key) == keepMin) ? o : key;
        }
    return key;
}
// exact 8th-smallest of the 64 lane values (r6-verified f32 bitonic + readlane 7)
__device__ __forceinline__ float eighth_smallest64(float v, int lane) {
    for (int k2 = 2; k2 <= 64; k2 <<= 1)
        for (int j = k2 >> 1; j > 0; j >>= 1) {
            float o = __shfl_xor(v, j);
            bool keepMin = ((lane & k2) == 0) == ((lane & j) == 0);
            v = ((o < v) == keepMin) ? o : v;
        }
    return __uint_as_float((unsigned)__builtin_amdgcn_readlane((int)__float_as_uint(v), 7));
}

// prepack: pts4[i] = (-2x, -2y, -2z, pn_screen) — screen-space only (Phase C re-derives
// np-exact values from the original points array)
__global__ void k_prepack(const float* __restrict__ points, float4* __restrict__ pts4) {
    int i = blockIdx.x * blockDim.x + threadIdx.x;   // grid exactly NP
    float px = points[i * 3 + 0], py = points[i * 3 + 1], pz = points[i * 3 + 2];
    float pn = __builtin_fmaf(pz, pz, __builtin_fmaf(py, py, px * px));
    pts4[i] = make_float4(-2.0f * px, -2.0f * py, -2.0f * pz, pn);
}

__global__ __launch_bounds__(TB) void knn_kernel(
    const float* __restrict__ xyz, const float* __restrict__ points,
    const float* __restrict__ feats, const float4* __restrict__ pts4,
    float* __restrict__ out)
{
#pragma clang fp contract(off)   // np-exact paths: explicit mul/add; fast paths: explicit fmaf
    __shared__ float4 spbuf[2][CHP];              // 16 KB double-buffered chunk
    __shared__ unsigned short sidx16[QBLK * CAP]; // 8 KB candidate indices
    __shared__ int scnt[QBLK];

    const int t     = threadIdx.x;
    const int lane  = t & 63;
    const int wid   = t >> 6;
    const int qbase = blockIdx.x * QBLK + wid * QW;

    if (t < QBLK) scnt[t] = 0;

    float qx[QW], qy[QW], qz[QW], qn[QW], mn[QW], tscr[QW];
#pragma unroll
    for (int qq = 0; qq < QW; ++qq) {
        int q = qbase + qq;
        float a = xyz[q * 3 + 0], b = xyz[q * 3 + 1], c = xyz[q * 3 + 2];
        qx[qq] = a; qy[qq] = b; qz[qq] = c;
        qn[qq] = (a * a + b * b) + c * c;   // np-exact: rounded squares, sequential add
        mn[qq] = __builtin_inff();
        tscr[qq] = __builtin_inff();
    }

    // async stage: chunk cid -> buffer bb (1 × 16B DMA per thread; linear dest)
#define STAGE(cid, bb)                                                              \
    __builtin_amdgcn_global_load_lds(                                               \
        (const __attribute__((address_space(1))) void*)(pts4 + (cid) * CHP + t),    \
        (__attribute__((address_space(3))) void*)(&spbuf[bb][t]), 16, 0, 0)

    // pipeline steps: 0..3 = chunks 0..3 min-only; 4..19 = chunks 0..15 screen-only
    STAGE(0, 0);
    __syncthreads();

    for (int c = 0; c < NC; ++c) {
        int b = c & 1;
        if (c + 1 < NC) {                     // issue-early: hide under compute
            int nk = c + 1;
            STAGE(nk < ACH ? nk : nk - ACH, nk & 1);
        }
        if (c < ACH) {
            // ---- min-only body: 3 fma + min per pair ----
#pragma unroll
            for (int s = 0; s < CHP / 64; ++s) {
                float4 p = spbuf[b][s * 64 + lane];
#pragma unroll
                for (int qq = 0; qq < QW; ++qq) {
                    float g = __builtin_fmaf(qx[qq], p.x,
                              __builtin_fmaf(qy[qq], p.y,
                              __builtin_fmaf(qz[qq], p.z, p.w)));
                    mn[qq] = fminf(mn[qq], g);
                }
            }
            if (c == ACH - 1) {
                // tight valid bound: 8th-smallest of 64 lane-mins (disjoint subsets =>
                // 8 distinct actual g-values <= tau => bounds full-set 8th smallest)
#pragma unroll
                for (int qq = 0; qq < QW; ++qq)
                    tscr[qq] = eighth_smallest64(mn[qq], lane) + 1e-3f;
            }
        } else {
            // ---- screen-only body: 3 fma + cmp + rare branch ----
            int cid = c - ACH;
#pragma unroll
            for (int s = 0; s < CHP / 64; ++s) {
                float4 p = spbuf[b][s * 64 + lane];
                int gidx = cid * CHP + s * 64 + lane;
#pragma unroll
                for (int qq = 0; qq < QW; ++qq) {
                    float g = __builtin_fmaf(qx[qq], p.x,
                              __builtin_fmaf(qy[qq], p.y,
                              __builtin_fmaf(qz[qq], p.z, p.w)));
                    if (__builtin_expect(g <= tscr[qq], 0)) {
                        int wq = wid * QW + qq;
                        int slot = atomicAdd(&scnt[wq], 1);
                        if (slot < CAP) sidx16[wq * CAP + slot] = (unsigned short)gidx;
                    }
                }
            }
        }
        __syncthreads();   // drains in-flight stage (issued pre-compute) + releases buf
    }
#undef STAGE

    // ---- Phase C: np-exact d2 recompute, u64 sort(s), top-8, output (r10-13 verified) ----
    const float4* feats4 = (const float4*)feats;
    float4* outf4 = (float4*)(out + (long)NQ * KNN * 3);
#pragma unroll 1
    for (int qq = 0; qq < QW; ++qq) {
        int wq = wid * QW + qq;
        int q  = qbase + qq;
        int cnt = scnt[wq]; if (cnt > CAP) cnt = CAP;

        u64 key1 = ~0ull;
        if (lane < cnt) {
            int idx = sidx16[wq * CAP + lane];
            float px = points[idx * 3 + 0], py = points[idx * 3 + 1], pz = points[idx * 3 + 2];
            float pn  = (px * px + py * py) + pz * pz;                 // np-exact
            float dot = __builtin_fmaf(qz[qq], pz, __builtin_fmaf(qy[qq], py, qx[qq] * px));
            float d2v = (qn[qq] - 2.0f * dot) + pn;
            unsigned bb = __float_as_uint(d2v);
            unsigned mk = (bb & 0x80000000u) ? ~bb : (bb | 0x80000000u);  // monotone map
            key1 = ((u64)mk << 32) | (unsigned)idx;                       // (value, stable idx)
        }
        u64 v = sort64_u64(key1, lane);

        if (cnt > 64) {                       // wave-uniform, rare (mean cnt ~32)
            u64 key2 = ~0ull;
            if (lane + 64 < cnt) {
                int idx = sidx16[wq * CAP + 64 + lane];
                float px = points[idx * 3 + 0], py = points[idx * 3 + 1], pz = points[idx * 3 + 2];
                float pn  = (px * px + py * py) + pz * pz;
                float dot = __builtin_fmaf(qz[qq], pz, __builtin_fmaf(qy[qq], py, qx[qq] * px));
                float d2v = (qn[qq] - 2.0f * dot) + pn;
                unsigned bb = __float_as_uint(d2v);
                unsigned mk = (bb & 0x80000000u) ? ~bb : (bb | 0x80000000u);
                key2 = ((u64)mk << 32) | (unsigned)idx;
            }
            u64 s2 = sort64_u64(key2, lane);
            // lanes 8..15 take s2[15-lane] (descending) -> lanes 0..15 bitonic; 4-step merge
            int src = (15 - lane) & 63;
            unsigned lo2 = __shfl((unsigned)s2, src);
            unsigned hi2 = __shfl((unsigned)(s2 >> 32), src);
            u64 kr = ((u64)hi2 << 32) | lo2;
            u64 m = (lane < 8) ? v : ((lane < 16) ? kr : ~0ull);
#pragma unroll
            for (int j = 8; j > 0; j >>= 1) {
                u64 o = shfl_xor_u64(m, j);
                bool low = (lane & j) == 0;
                m = low ? (o < m ? o : m) : (o < m ? m : o);
            }
            v = m;
        }

        // lanes 0..7 hold top-8 ascending (r5/r6-verified output layout)
        int nb = __shfl((int)(unsigned)v, lane >> 3);
        outf4[(long)q * (KNN * FD / 4) + lane] = feats4[(long)nb * (FD / 4) + (lane & 7)];
        int j2 = lane / 3;
        int nb2 = __shfl((int)(unsigned)v, j2);
        if (lane < 24) {
            out[(long)q * (KNN * 3) + lane] = points[nb2 * 3 + (lane - j2 * 3)];
        }
    }
}

extern "C" void kernel_launch(void* const* d_in, const int* in_sizes, int n_in,
                              void* d_out, int out_size, void* d_ws, size_t ws_size,
                              hipStream_t stream) {
    const float* xyz    = (const float*)d_in[0];
    const float* points = (const float*)d_in[1];
    const float* feats  = (const float*)d_in[2];
    float* out = (float*)d_out;
    float4* pts4 = (float4*)d_ws;   // 128 KB scratch

    hipLaunchKernelGGL(k_prepack, dim3(NP / 256), dim3(256), 0, stream, points, pts4);
    hipLaunchKernelGGL(knn_kernel, dim3(NQ / QBLK), dim3(TB), 0, stream,
                       xyz, points, feats, pts4, out);
}